// Round 8
// baseline (676.615 us; speedup 1.0000x reference)
//
#include <hip/hip_runtime.h>

// ---- static config (matches reference) ----
constexpr int kNImgs   = 9;
constexpr int kC       = 24;
constexpr int kHF      = 112, kWF = 112;
constexpr int kHD      = 56,  kWD = 56;
constexpr int kNPix    = kHD * kWD;              // 3136
constexpr int kNPlanes = 64;
constexpr int kPtsPerRef = kNPlanes * kNPix;     // 200704
constexpr int kEdgesPerRef = 8;
constexpr int kNEdges  = kNImgs * kEdgesPerRef;  // 72
constexpr int kFeatPix = kHF * kWF;              // 12544
constexpr int kFeatPerImg = kC * kFeatPix;       // 301056

// block geometry: 512 threads = 32 d (lane-major) x 16 p
constexpr int kDTile = 32, kPTile = 16;
constexpr int kDHalves = kNPlanes / kDTile;        // 2
constexpr int kPGroups = kNPix / kPTile;           // 196
constexpr int kBlocksPerRef = kDHalves * kPGroups; // 392

typedef _Float16 half8  __attribute__((ext_vector_type(8)));
typedef _Float16 half2v __attribute__((ext_vector_type(2)));
typedef float    float2v __attribute__((ext_vector_type(2)));

#if __has_builtin(__builtin_amdgcn_fdot2)
__device__ inline float fdot2(half2v a, half2v b, float c) {
  return __builtin_amdgcn_fdot2(a, b, c, false);
}
#else
__device__ inline float fdot2(half2v a, half2v b, float c) {
  return c + (float)a[0] * (float)b[0] + (float)a[1] * (float)b[1];
}
#endif

// ---------- small 3x3 helpers ----------
__device__ inline void mm3(const float* A, const float* B, float* C) {
#pragma unroll
  for (int i = 0; i < 3; ++i)
#pragma unroll
    for (int j = 0; j < 3; ++j)
      C[i*3+j] = A[i*3+0]*B[0*3+j] + A[i*3+1]*B[1*3+j] + A[i*3+2]*B[2*3+j];
}

__device__ inline void inv3(const float* A, float* I) {
  float a=A[0],b=A[1],c=A[2],d=A[3],e=A[4],f=A[5],g=A[6],h=A[7],i=A[8];
  float c00 = e*i - f*h;
  float c01 = -(d*i - f*g);
  float c02 = d*h - e*g;
  float det = a*c00 + b*c01 + c*c02;
  float r = 1.0f / det;
  I[0] = c00*r;           I[1] = (c*h - b*i)*r;  I[2] = (b*f - c*e)*r;
  I[3] = c01*r;           I[4] = (a*i - c*g)*r;  I[5] = (c*d - a*f)*r;
  I[6] = c02*r;           I[7] = (b*g - a*h)*r;  I[8] = (a*e - b*d)*r;
}

// ---------- transpose+convert feats [N,C,HF,WF] f32 -> [N,HF,WF,C] f16 ----------
__global__ __launch_bounds__(256)
void transpose_feats_kernel(const float* __restrict__ f, _Float16* __restrict__ ft) {
  int idx = blockIdx.x * 256 + threadIdx.x;
  if (idx >= kNImgs * kFeatPerImg) return;
  int n  = idx / kFeatPerImg;
  int r  = idx - n * kFeatPerImg;
  int c  = r / kFeatPix;
  int yx = r - c * kFeatPix;
  ft[((size_t)n * kFeatPix + yx) * kC + c] = (_Float16)f[idx];
}

struct EdgeData {
  const half8* p00; const half8* p01; const half8* p10; const half8* p11;
  half2v wr0, wr1;
  float mult;
};

struct Buf { half8 f00[3], f01[3], f10[3], f11[3]; };

// ---------- main fused kernel ----------
// block = (ref n, d-half, p-group); lanes d-major (wave = 32 d x 2 p) so a
// wave's gathers walk an epipolar segment (sub-pixel step -> line sharing).
// Edge loop is software-pipelined 2-deep (register double buffer) so edge
// j+1's 12 loads are in flight during edge j's fdot2 compute.
template <bool TR>
__global__ __launch_bounds__(512)
void psv_var_kernel(const float* __restrict__ feats,      // [N,C,HF,WF] f32 (!TR)
                    const _Float16* __restrict__ featsT,  // [N,HF,WF,C] f16 (TR)
                    const float* __restrict__ rotmats,    // [N,3,3]
                    const float* __restrict__ tvecs,      // [N,3]
                    const float* __restrict__ Kmat,       // [N,3,3]
                    const int*   __restrict__ edges,      // [2,72]
                    float* __restrict__ out) {            // [N,C,D,HD,WD]
  __shared__ float sM[kEdgesPerRef][9];
  __shared__ float sB[kEdgesPerRef][3];
  __shared__ int   sSrc[kEdgesPerRef];
  __shared__ int   sUIdx[kEdgesPerRef];
  __shared__ float sMult[kEdgesPerRef];
  __shared__ int   sKU;
  // transpose buffer: bank = (2*p + d) % 32 -> exactly 2 lanes/bank on both
  // write (psub*34+dsub) and read (pp2*34+dd2) sides: conflict-free.
  __shared__ float sT[4][kPTile][kDTile + 2];

  // bijective XCD-chunk swizzle (m204 formula; works for any gridDim)
  const int nwg = gridDim.x;
  const int orig = blockIdx.x;
  const int q = nwg >> 3, r8 = nwg & 7;
  const int xcd = orig & 7, lin = orig >> 3;
  const int bid = ((xcd < r8) ? xcd * (q + 1) : r8 * (q + 1) + (xcd - r8) * q) + lin;

  const int n     = bid / kBlocksPerRef;
  const int rem   = bid - n * kBlocksPerRef;
  const int dHalf = rem / kPGroups;
  const int pG    = rem - dHalf * kPGroups;

  const int t = threadIdx.x;

  if (t < kEdgesPerRef) {
    const int e  = n * kEdgesPerRef + t;
    const int re = edges[e];            // ref row
    const int se = edges[kNEdges + e];  // src row
    sSrc[t] = se;

    const float* Rr = rotmats + re * 9;
    const float* Rs = rotmats + se * 9;
    const float* Kr = Kmat + re * 9;
    const float* Ks = Kmat + se * 9;
    const float* tr = tvecs + re * 3;
    const float* ts = tvecs + se * 3;

    float RrT[9];
#pragma unroll
    for (int i = 0; i < 3; ++i)
#pragma unroll
      for (int j = 0; j < 3; ++j) RrT[i*3+j] = Rr[j*3+i];

    float Kinv[9], A[9], T1[9], M[9];
    inv3(Kr, Kinv);
    mm3(Rs, RrT, A);       // A = R_src * R_ref^T
    mm3(A, Kinv, T1);
    mm3(Ks, T1, M);        // M = K_src * A * K_ref^-1

    float At0 = A[0]*tr[0] + A[1]*tr[1] + A[2]*tr[2];
    float At1 = A[3]*tr[0] + A[4]*tr[1] + A[5]*tr[2];
    float At2 = A[6]*tr[0] + A[7]*tr[1] + A[8]*tr[2];
    float bv0 = ts[0] - At0, bv1 = ts[1] - At1, bv2 = ts[2] - At2;
#pragma unroll
    for (int i = 0; i < 9; ++i) sM[t][i] = M[i];
#pragma unroll
    for (int i = 0; i < 3; ++i)
      sB[t][i] = Ks[i*3+0]*bv0 + Ks[i*3+1]*bv1 + Ks[i*3+2]*bv2;
  }
  __syncthreads();

  if (t == 0) {
    int k = 0;
    for (int j = 0; j < kEdgesPerRef; ++j) {
      const int s = sSrc[j];
      bool dup = false;
      for (int i = 0; i < k; ++i) {
        if (sSrc[sUIdx[i]] == s) { sMult[i] += 1.0f; dup = true; break; }
      }
      if (!dup) { sUIdx[k] = j; sMult[k] = 1.0f; ++k; }
    }
    sKU = k;
  }
  __syncthreads();

  // d-major lane mapping
  const int dsub = t & 31;
  const int psub = t >> 5;
  const int d = dHalf * kDTile + dsub;
  const int p = pG * kPTile + psub;
  const int h = p / kWD;
  const int w = p - h * kWD;

  const float u = (float)w * (447.0f / 55.0f);   // linspace(0,447,56)
  const float v = (float)h * (447.0f / 55.0f);
  const float depth = 0.5f + 0.05f * (float)d;

  float2v acc2[kC / 2], accsq2[kC / 2];
#pragma unroll
  for (int i = 0; i < kC / 2; ++i) {
    acc2[i] = (float2v){0.0f, 0.0f};
    accsq2[i] = (float2v){0.0f, 0.0f};
  }

  const int kU = sKU;

  if constexpr (TR) {
    auto prepare = [&](int jj) -> EdgeData {
      EdgeData E;
      const int j = sUIdx[jj];
      E.mult = sMult[jj];
      const float* M = sM[j];
      const float px = depth * (M[0]*u + M[1]*v + M[2]) + sB[j][0];
      const float py = depth * (M[3]*u + M[4]*v + M[5]) + sB[j][1];
      const float pz = depth * (M[6]*u + M[7]*v + M[8]) + sB[j][2];
      const float rz = 1.0f / (fabsf(pz) + 1e-8f);
      const float x = px * rz * (111.0f / 447.0f);
      const float y = py * rz * (111.0f / 447.0f);
      const float x0 = floorf(x), y0 = floorf(y);
      const float wx = x - x0, wy = y - y0;
      const bool vx0 = (x0 >= 0.0f)  && (x0 <= 111.0f);
      const bool vx1 = (x0 >= -1.0f) && (x0 <= 110.0f);
      const bool vy0 = (y0 >= 0.0f)  && (y0 <= 111.0f);
      const bool vy1 = (y0 >= -1.0f) && (y0 <= 110.0f);
      const float w00 = (vx0 && vy0) ? (1.0f - wx) * (1.0f - wy) : 0.0f;
      const float w01 = (vx1 && vy0) ? wx * (1.0f - wy) : 0.0f;
      const float w10 = (vx0 && vy1) ? (1.0f - wx) * wy : 0.0f;
      const float w11 = (vx1 && vy1) ? wx * wy : 0.0f;
      const int xc0 = (int)fminf(fmaxf(x0,        0.0f), 111.0f);
      const int xc1 = (int)fminf(fmaxf(x0 + 1.0f, 0.0f), 111.0f);
      const int yc0 = (int)fminf(fmaxf(y0,        0.0f), 111.0f);
      const int yc1 = (int)fminf(fmaxf(y0 + 1.0f, 0.0f), 111.0f);
      const _Float16* base = featsT + (size_t)sSrc[j] * kFeatPix * kC;
      E.p00 = (const half8*)(base + (yc0 * kWF + xc0) * kC);
      E.p01 = (const half8*)(base + (yc0 * kWF + xc1) * kC);
      E.p10 = (const half8*)(base + (yc1 * kWF + xc0) * kC);
      E.p11 = (const half8*)(base + (yc1 * kWF + xc1) * kC);
      E.wr0 = (half2v){(_Float16)w00, (_Float16)w01};
      E.wr1 = (half2v){(_Float16)w10, (_Float16)w11};
      return E;
    };

    auto loadBuf = [&](Buf& Bf, const EdgeData& E) {
#pragma unroll
      for (int i = 0; i < 3; ++i) {
        Bf.f00[i] = E.p00[i];
        Bf.f01[i] = E.p01[i];
        Bf.f10[i] = E.p10[i];
        Bf.f11[i] = E.p11[i];
      }
    };

    auto computeBuf = [&](const Buf& Bf, const EdgeData& E) {
      const float2v mult2 = {E.mult, E.mult};
#pragma unroll
      for (int i = 0; i < 3; ++i) {
#pragma unroll
        for (int k2 = 0; k2 < 4; ++k2) {
          const int k0 = 2*k2, k1 = 2*k2 + 1;
          const half2v a00 = {Bf.f00[i][k0], Bf.f01[i][k0]};
          const half2v a10 = {Bf.f10[i][k0], Bf.f11[i][k0]};
          const half2v a01 = {Bf.f00[i][k1], Bf.f01[i][k1]};
          const half2v a11 = {Bf.f10[i][k1], Bf.f11[i][k1]};
          const float v0 = fdot2(a10, E.wr1, fdot2(a00, E.wr0, 0.0f));
          const float v1 = fdot2(a11, E.wr1, fdot2(a01, E.wr0, 0.0f));
          const float2v val2 = {v0, v1};
          const float2v mval2 = mult2 * val2;
          const int idx = i*4 + k2;
          acc2[idx] += mval2;
          accsq2[idx] = mval2 * val2 + accsq2[idx];
        }
      }
    };

    // 2-deep software pipeline over unique edges (uniform branches: kU is
    // block-uniform). Two NAMED buffers -> all register indexing static.
    Buf A, B;
    EdgeData e0 = prepare(0);
    loadBuf(A, e0);
    int jj = 0;
    while (true) {
      const bool hasNext = (jj + 1) < kU;
      EdgeData e1;
      if (hasNext) { e1 = prepare(jj + 1); loadBuf(B, e1); }
      computeBuf(A, e0);
      if (!hasNext) break;
      ++jj;
      const bool hasNext2 = (jj + 1) < kU;
      if (hasNext2) { e0 = prepare(jj + 1); loadBuf(A, e0); }
      computeBuf(B, e1);
      if (!hasNext2) break;
      ++jj;
    }
  } else {
    for (int jj = 0; jj < kU; ++jj) {
      const int j = sUIdx[jj];
      const float mult = sMult[jj];
      const float* M = sM[j];
      const float px = depth * (M[0]*u + M[1]*v + M[2]) + sB[j][0];
      const float py = depth * (M[3]*u + M[4]*v + M[5]) + sB[j][1];
      const float pz = depth * (M[6]*u + M[7]*v + M[8]) + sB[j][2];
      const float rz = 1.0f / (fabsf(pz) + 1e-8f);
      const float x = px * rz * (111.0f / 447.0f);
      const float y = py * rz * (111.0f / 447.0f);
      const float x0 = floorf(x), y0 = floorf(y);
      const float wx = x - x0, wy = y - y0;
      const bool vx0 = (x0 >= 0.0f)  && (x0 <= 111.0f);
      const bool vx1 = (x0 >= -1.0f) && (x0 <= 110.0f);
      const bool vy0 = (y0 >= 0.0f)  && (y0 <= 111.0f);
      const bool vy1 = (y0 >= -1.0f) && (y0 <= 110.0f);
      const float w00 = (vx0 && vy0) ? (1.0f - wx) * (1.0f - wy) : 0.0f;
      const float w01 = (vx1 && vy0) ? wx * (1.0f - wy) : 0.0f;
      const float w10 = (vx0 && vy1) ? (1.0f - wx) * wy : 0.0f;
      const float w11 = (vx1 && vy1) ? wx * wy : 0.0f;
      const int xc0 = (int)fminf(fmaxf(x0,        0.0f), 111.0f);
      const int xc1 = (int)fminf(fmaxf(x0 + 1.0f, 0.0f), 111.0f);
      const int yc0 = (int)fminf(fmaxf(y0,        0.0f), 111.0f);
      const int yc1 = (int)fminf(fmaxf(y0 + 1.0f, 0.0f), 111.0f);
      const float* base = feats + (size_t)sSrc[j] * kFeatPerImg;
      const int o00 = yc0 * kWF + xc0;
      const int o01 = yc0 * kWF + xc1;
      const int o10 = yc1 * kWF + xc0;
      const int o11 = yc1 * kWF + xc1;
#pragma unroll
      for (int i = 0; i < kC / 2; ++i) {
#pragma unroll
        for (int kk = 0; kk < 2; ++kk) {
          const int c = 2*i + kk;
          const float* bc = base + (size_t)c * kFeatPix;
          float val = w00*bc[o00] + w01*bc[o01] + w10*bc[o10] + w11*bc[o11];
          const float mval = mult * val;
          acc2[i][kk] += mval;
          accsq2[i][kk] = __builtin_fmaf(mval, val, accsq2[i][kk]);
        }
      }
    }
  }

  // ---- epilogue: LDS transpose (d-major lanes -> p-coalesced stores) ----
  const int pp2 = t & (kPTile - 1);   // store-side pixel index
  const int dd2 = t >> 4;             // store-side depth index (0..31)
  const size_t outBase = (size_t)n * kC * (size_t)kPtsPerRef;
#pragma unroll
  for (int ch = 0; ch < kC / 4; ++ch) {
    __syncthreads();               // protect previous chunk's reads
#pragma unroll
    for (int cc = 0; cc < 4; ++cc) {
      const int c = ch * 4 + cc;
      const float a = acc2[c >> 1][c & 1];
      const float s = accsq2[c >> 1][c & 1];
      const float mean = a * 0.125f;
      sT[cc][psub][dsub] = s * 0.125f - mean * mean;
    }
    __syncthreads();
#pragma unroll
    for (int cc = 0; cc < 4; ++cc) {
      const int c = ch * 4 + cc;
      out[outBase + ((size_t)c * kNPlanes + (dHalf * kDTile + dd2)) * kNPix
          + pG * kPTile + pp2] = sT[cc][pp2][dd2];
    }
  }
}

extern "C" void kernel_launch(void* const* d_in, const int* in_sizes, int n_in,
                              void* d_out, int out_size, void* d_ws, size_t ws_size,
                              hipStream_t stream) {
  const float* feats  = (const float*)d_in[0];
  const float* rot    = (const float*)d_in[1];
  const float* tv     = (const float*)d_in[2];
  const float* Kmat   = (const float*)d_in[3];
  const int*   edges  = (const int*)d_in[4];
  float* out = (float*)d_out;

  const size_t featsTBytes = (size_t)kNImgs * kFeatPix * kC * sizeof(_Float16);  // 5.4 MB
  const int gridMain = kNImgs * kBlocksPerRef;     // 3528 blocks of 512 threads

  if (ws_size >= featsTBytes) {
    _Float16* featsT = (_Float16*)d_ws;
    const int nT = kNImgs * kFeatPerImg;           // 2,709,504
    transpose_feats_kernel<<<(nT + 255) / 256, 256, 0, stream>>>(feats, featsT);
    psv_var_kernel<true><<<gridMain, 512, 0, stream>>>(feats, featsT, rot, tv, Kmat, edges, out);
  } else {
    psv_var_kernel<false><<<gridMain, 512, 0, stream>>>(feats, nullptr, rot, tv, Kmat, edges, out);
  }
}

// Round 9
// 191.236 us; speedup vs baseline: 3.5381x; 3.5381x over previous
//
#include <hip/hip_runtime.h>

// ---- static config (matches reference) ----
constexpr int kNImgs   = 9;
constexpr int kC       = 24;
constexpr int kHF      = 112, kWF = 112;
constexpr int kHD      = 56,  kWD = 56;
constexpr int kNPix    = kHD * kWD;              // 3136
constexpr int kNPlanes = 64;
constexpr int kPtsPerRef = kNPlanes * kNPix;     // 200704
constexpr int kEdgesPerRef = 8;
constexpr int kNEdges  = kNImgs * kEdgesPerRef;  // 72
constexpr int kFeatPix = kHF * kWF;              // 12544
constexpr int kFeatPerImg = kC * kFeatPix;       // 301056

// block geometry: 512 threads = 32 dsub (lane-major) x 16 p; each thread
// handles depths {dsub, dsub+32} -> block covers all 64 planes x 16 pixels.
constexpr int kDTile = 32, kPTile = 16;
constexpr int kPGroups = kNPix / kPTile;           // 196
constexpr int kBlocksPerRef = kPGroups;            // 196

typedef _Float16 half8  __attribute__((ext_vector_type(8)));
typedef _Float16 half2v __attribute__((ext_vector_type(2)));
typedef float    float2v __attribute__((ext_vector_type(2)));

#if __has_builtin(__builtin_amdgcn_fdot2)
__device__ inline float fdot2(half2v a, half2v b, float c) {
  return __builtin_amdgcn_fdot2(a, b, c, false);
}
#else
__device__ inline float fdot2(half2v a, half2v b, float c) {
  return c + (float)a[0] * (float)b[0] + (float)a[1] * (float)b[1];
}
#endif

// ---------- small 3x3 helpers ----------
__device__ inline void mm3(const float* A, const float* B, float* C) {
#pragma unroll
  for (int i = 0; i < 3; ++i)
#pragma unroll
    for (int j = 0; j < 3; ++j)
      C[i*3+j] = A[i*3+0]*B[0*3+j] + A[i*3+1]*B[1*3+j] + A[i*3+2]*B[2*3+j];
}

__device__ inline void inv3(const float* A, float* I) {
  float a=A[0],b=A[1],c=A[2],d=A[3],e=A[4],f=A[5],g=A[6],h=A[7],i=A[8];
  float c00 = e*i - f*h;
  float c01 = -(d*i - f*g);
  float c02 = d*h - e*g;
  float det = a*c00 + b*c01 + c*c02;
  float r = 1.0f / det;
  I[0] = c00*r;           I[1] = (c*h - b*i)*r;  I[2] = (b*f - c*e)*r;
  I[3] = c01*r;           I[4] = (a*i - c*g)*r;  I[5] = (c*d - a*f)*r;
  I[6] = c02*r;           I[7] = (b*g - a*h)*r;  I[8] = (a*e - b*d)*r;
}

// ---------- transpose+convert feats [N,C,HF,WF] f32 -> [N,HF,WF,C] f16 ----------
__global__ __launch_bounds__(256)
void transpose_feats_kernel(const float* __restrict__ f, _Float16* __restrict__ ft) {
  int idx = blockIdx.x * 256 + threadIdx.x;
  if (idx >= kNImgs * kFeatPerImg) return;
  int n  = idx / kFeatPerImg;
  int r  = idx - n * kFeatPerImg;
  int c  = r / kFeatPix;
  int yx = r - c * kFeatPix;
  ft[((size_t)n * kFeatPix + yx) * kC + c] = (_Float16)f[idx];
}

// ---------- main fused kernel ----------
// block = (ref n, p-group); lanes d-major (wave = 32 d x 2 p) so a wave's
// gathers walk an epipolar segment (sub-pixel step -> line sharing). Each
// thread computes 2 depths (independent load->fdot2 chains: ILP hides
// gather latency). Plain loop structure — no manual pipeline (R8 lesson:
// rotating register buffers spill). LDS transpose epilogue restores
// p-coalesced stores with a conflict-free (2p+d)-bank layout.
template <bool TR>
__global__ __launch_bounds__(512)
void psv_var_kernel(const float* __restrict__ feats,      // [N,C,HF,WF] f32 (!TR)
                    const _Float16* __restrict__ featsT,  // [N,HF,WF,C] f16 (TR)
                    const float* __restrict__ rotmats,    // [N,3,3]
                    const float* __restrict__ tvecs,      // [N,3]
                    const float* __restrict__ Kmat,       // [N,3,3]
                    const int*   __restrict__ edges,      // [2,72]
                    float* __restrict__ out) {            // [N,C,D,HD,WD]
  __shared__ float sM[kEdgesPerRef][9];
  __shared__ float sB[kEdgesPerRef][3];
  __shared__ int   sSrc[kEdgesPerRef];
  __shared__ int   sUIdx[kEdgesPerRef];
  __shared__ float sMult[kEdgesPerRef];
  __shared__ int   sKU;
  // bank = (2*p + d) % 32 -> exactly 2 lanes/bank on write (psub*34+dsub)
  // and read (pp2*34+dd2): conflict-free (measured 0 conflicts in R8).
  __shared__ float sT[4][kPTile][kDTile + 2];

  // bijective XCD-chunk swizzle (m204 formula; works for any gridDim)
  const int nwg = gridDim.x;
  const int orig = blockIdx.x;
  const int q = nwg >> 3, r8 = nwg & 7;
  const int xcd = orig & 7, lin = orig >> 3;
  const int bid = ((xcd < r8) ? xcd * (q + 1) : r8 * (q + 1) + (xcd - r8) * q) + lin;

  const int n  = bid / kBlocksPerRef;
  const int pG = bid - n * kBlocksPerRef;

  const int t = threadIdx.x;

  if (t < kEdgesPerRef) {
    const int e  = n * kEdgesPerRef + t;
    const int re = edges[e];            // ref row
    const int se = edges[kNEdges + e];  // src row
    sSrc[t] = se;

    const float* Rr = rotmats + re * 9;
    const float* Rs = rotmats + se * 9;
    const float* Kr = Kmat + re * 9;
    const float* Ks = Kmat + se * 9;
    const float* tr = tvecs + re * 3;
    const float* ts = tvecs + se * 3;

    float RrT[9];
#pragma unroll
    for (int i = 0; i < 3; ++i)
#pragma unroll
      for (int j = 0; j < 3; ++j) RrT[i*3+j] = Rr[j*3+i];

    float Kinv[9], A[9], T1[9], M[9];
    inv3(Kr, Kinv);
    mm3(Rs, RrT, A);       // A = R_src * R_ref^T
    mm3(A, Kinv, T1);
    mm3(Ks, T1, M);        // M = K_src * A * K_ref^-1

    float At0 = A[0]*tr[0] + A[1]*tr[1] + A[2]*tr[2];
    float At1 = A[3]*tr[0] + A[4]*tr[1] + A[5]*tr[2];
    float At2 = A[6]*tr[0] + A[7]*tr[1] + A[8]*tr[2];
    float bv0 = ts[0] - At0, bv1 = ts[1] - At1, bv2 = ts[2] - At2;
#pragma unroll
    for (int i = 0; i < 9; ++i) sM[t][i] = M[i];
#pragma unroll
    for (int i = 0; i < 3; ++i)
      sB[t][i] = Ks[i*3+0]*bv0 + Ks[i*3+1]*bv1 + Ks[i*3+2]*bv2;
  }
  __syncthreads();

  if (t == 0) {
    int k = 0;
    for (int j = 0; j < kEdgesPerRef; ++j) {
      const int s = sSrc[j];
      bool dup = false;
      for (int i = 0; i < k; ++i) {
        if (sSrc[sUIdx[i]] == s) { sMult[i] += 1.0f; dup = true; break; }
      }
      if (!dup) { sUIdx[k] = j; sMult[k] = 1.0f; ++k; }
    }
    sKU = k;
  }
  __syncthreads();

  // d-major lane mapping
  const int dsub = t & 31;
  const int psub = t >> 5;
  const int p = pG * kPTile + psub;
  const int h = p / kWD;
  const int w = p - h * kWD;

  const float u = (float)w * (447.0f / 55.0f);   // linspace(0,447,56)
  const float v = (float)h * (447.0f / 55.0f);
  const float depthA = 0.5f + 0.05f * (float)dsub;          // d = dsub
  const float depthB = 0.5f + 0.05f * (float)(dsub + 32);   // d = dsub+32

  float2v acc2[2][kC / 2], accsq2[2][kC / 2];
#pragma unroll
  for (int dd = 0; dd < 2; ++dd)
#pragma unroll
    for (int i = 0; i < kC / 2; ++i) {
      acc2[dd][i] = (float2v){0.0f, 0.0f};
      accsq2[dd][i] = (float2v){0.0f, 0.0f};
    }

  const int kU = sKU;

  for (int jj = 0; jj < kU; ++jj) {
    const int j = sUIdx[jj];
    const float mult = sMult[jj];
    const float* M = sM[j];
    // depth-independent ray dots, shared by both depths
    const float t0 = M[0]*u + M[1]*v + M[2];
    const float t1 = M[3]*u + M[4]*v + M[5];
    const float t2 = M[6]*u + M[7]*v + M[8];
    const float b0 = sB[j][0], b1 = sB[j][1], b2 = sB[j][2];
    const int src = sSrc[j];

#pragma unroll
    for (int dd = 0; dd < 2; ++dd) {
      const float depth = dd ? depthB : depthA;
      const float px = depth * t0 + b0;
      const float py = depth * t1 + b1;
      const float pz = depth * t2 + b2;
      const float rz = 1.0f / (fabsf(pz) + 1e-8f);

      const float x = px * rz * (111.0f / 447.0f);
      const float y = py * rz * (111.0f / 447.0f);

      const float x0 = floorf(x), y0 = floorf(y);
      const float wx = x - x0, wy = y - y0;
      const bool vx0 = (x0 >= 0.0f)  && (x0 <= 111.0f);
      const bool vx1 = (x0 >= -1.0f) && (x0 <= 110.0f);
      const bool vy0 = (y0 >= 0.0f)  && (y0 <= 111.0f);
      const bool vy1 = (y0 >= -1.0f) && (y0 <= 110.0f);
      const float w00 = (vx0 && vy0) ? (1.0f - wx) * (1.0f - wy) : 0.0f;
      const float w01 = (vx1 && vy0) ? wx * (1.0f - wy) : 0.0f;
      const float w10 = (vx0 && vy1) ? (1.0f - wx) * wy : 0.0f;
      const float w11 = (vx1 && vy1) ? wx * wy : 0.0f;

      const int xc0 = (int)fminf(fmaxf(x0,        0.0f), 111.0f);
      const int xc1 = (int)fminf(fmaxf(x0 + 1.0f, 0.0f), 111.0f);
      const int yc0 = (int)fminf(fmaxf(y0,        0.0f), 111.0f);
      const int yc1 = (int)fminf(fmaxf(y0 + 1.0f, 0.0f), 111.0f);

      if constexpr (TR) {
        const half2v wr0 = {(_Float16)w00, (_Float16)w01};
        const half2v wr1 = {(_Float16)w10, (_Float16)w11};
        const float2v mult2 = {mult, mult};
        const _Float16* base = featsT + (size_t)src * kFeatPix * kC;
        const int o00 = (yc0 * kWF + xc0) * kC;
        const int o01 = (yc0 * kWF + xc1) * kC;
        const int o10 = (yc1 * kWF + xc0) * kC;
        const int o11 = (yc1 * kWF + xc1) * kC;
#pragma unroll
        for (int i = 0; i < kC / 8; ++i) {          // 3 chunks of 8 f16 channels
          const half8 f00 = *(const half8*)(base + o00 + 8*i);
          const half8 f01 = *(const half8*)(base + o01 + 8*i);
          const half8 f10 = *(const half8*)(base + o10 + 8*i);
          const half8 f11 = *(const half8*)(base + o11 + 8*i);
#pragma unroll
          for (int k2 = 0; k2 < 4; ++k2) {
            const int k0 = 2*k2, k1 = 2*k2 + 1;
            const half2v a00 = {f00[k0], f01[k0]};
            const half2v a10 = {f10[k0], f11[k0]};
            const half2v a01 = {f00[k1], f01[k1]};
            const half2v a11 = {f10[k1], f11[k1]};
            const float v0 = fdot2(a10, wr1, fdot2(a00, wr0, 0.0f));
            const float v1 = fdot2(a11, wr1, fdot2(a01, wr0, 0.0f));
            const float2v val2 = {v0, v1};
            const float2v mval2 = mult2 * val2;
            const int idx = i*4 + k2;
            acc2[dd][idx] += mval2;
            accsq2[dd][idx] = mval2 * val2 + accsq2[dd][idx];
          }
        }
      } else {
        const float* base = feats + (size_t)src * kFeatPerImg;
        const int o00 = yc0 * kWF + xc0;
        const int o01 = yc0 * kWF + xc1;
        const int o10 = yc1 * kWF + xc0;
        const int o11 = yc1 * kWF + xc1;
#pragma unroll
        for (int i = 0; i < kC / 2; ++i) {
#pragma unroll
          for (int kk = 0; kk < 2; ++kk) {
            const int c = 2*i + kk;
            const float* bc = base + (size_t)c * kFeatPix;
            float val = w00*bc[o00] + w01*bc[o01] + w10*bc[o10] + w11*bc[o11];
            const float mval = mult * val;
            acc2[dd][i][kk] += mval;
            accsq2[dd][i][kk] = __builtin_fmaf(mval, val, accsq2[dd][i][kk]);
          }
        }
      }
    }
  }

  // ---- epilogue: LDS transpose (d-major lanes -> p-coalesced stores) ----
  const int pp2 = t & (kPTile - 1);   // store-side pixel index
  const int dd2 = t >> 4;             // store-side depth index (0..31)
  const size_t outBase = (size_t)n * kC * (size_t)kPtsPerRef;
#pragma unroll
  for (int dd = 0; dd < 2; ++dd) {
#pragma unroll
    for (int ch = 0; ch < kC / 4; ++ch) {
      __syncthreads();               // protect previous chunk's reads
#pragma unroll
      for (int cc = 0; cc < 4; ++cc) {
        const int c = ch * 4 + cc;
        const float a = acc2[dd][c >> 1][c & 1];
        const float s = accsq2[dd][c >> 1][c & 1];
        const float mean = a * 0.125f;
        sT[cc][psub][dsub] = s * 0.125f - mean * mean;
      }
      __syncthreads();
#pragma unroll
      for (int cc = 0; cc < 4; ++cc) {
        const int c = ch * 4 + cc;
        out[outBase + ((size_t)c * kNPlanes + (dd * kDTile + dd2)) * kNPix
            + pG * kPTile + pp2] = sT[cc][pp2][dd2];
      }
    }
  }
}

extern "C" void kernel_launch(void* const* d_in, const int* in_sizes, int n_in,
                              void* d_out, int out_size, void* d_ws, size_t ws_size,
                              hipStream_t stream) {
  const float* feats  = (const float*)d_in[0];
  const float* rot    = (const float*)d_in[1];
  const float* tv     = (const float*)d_in[2];
  const float* Kmat   = (const float*)d_in[3];
  const int*   edges  = (const int*)d_in[4];
  float* out = (float*)d_out;

  const size_t featsTBytes = (size_t)kNImgs * kFeatPix * kC * sizeof(_Float16);  // 5.4 MB
  const int gridMain = kNImgs * kBlocksPerRef;     // 1764 blocks of 512 threads

  if (ws_size >= featsTBytes) {
    _Float16* featsT = (_Float16*)d_ws;
    const int nT = kNImgs * kFeatPerImg;           // 2,709,504
    transpose_feats_kernel<<<(nT + 255) / 256, 256, 0, stream>>>(feats, featsT);
    psv_var_kernel<true><<<gridMain, 512, 0, stream>>>(feats, featsT, rot, tv, Kmat, edges, out);
  } else {
    psv_var_kernel<false><<<gridMain, 512, 0, stream>>>(feats, nullptr, rot, tv, Kmat, edges, out);
  }
}

// Round 10
// 151.631 us; speedup vs baseline: 4.4623x; 1.2612x over previous
//
#include <hip/hip_runtime.h>

// ---- static config (matches reference) ----
constexpr int kNImgs   = 9;
constexpr int kC       = 24;
constexpr int kHF      = 112, kWF = 112;
constexpr int kHD      = 56,  kWD = 56;
constexpr int kNPix    = kHD * kWD;              // 3136
constexpr int kNPlanes = 64;
constexpr int kPtsPerRef = kNPlanes * kNPix;     // 200704
constexpr int kEdgesPerRef = 8;
constexpr int kNEdges  = kNImgs * kEdgesPerRef;  // 72
constexpr int kFeatPix = kHF * kWF;              // 12544
constexpr int kFeatPerImg = kC * kFeatPix;       // 301056

// block geometry: 256 threads = 32 d (lane-major) x 8 p
constexpr int kDTile = 32, kPTile = 8;
constexpr int kDHalves = kNPlanes / kDTile;        // 2
constexpr int kPGroups = kNPix / kPTile;           // 392
constexpr int kBlocksPerRef = kDHalves * kPGroups; // 784

typedef _Float16 half8  __attribute__((ext_vector_type(8)));
typedef _Float16 half2v __attribute__((ext_vector_type(2)));
typedef float    float2v __attribute__((ext_vector_type(2)));
typedef unsigned int uint4v __attribute__((ext_vector_type(4)));

__device__ inline half2v u2h(unsigned int u) {
  union { unsigned int u; half2v h; } cv; cv.u = u; return cv.h;
}

// ---------- small 3x3 helpers ----------
__device__ inline void mm3(const float* A, const float* B, float* C) {
#pragma unroll
  for (int i = 0; i < 3; ++i)
#pragma unroll
    for (int j = 0; j < 3; ++j)
      C[i*3+j] = A[i*3+0]*B[0*3+j] + A[i*3+1]*B[1*3+j] + A[i*3+2]*B[2*3+j];
}

__device__ inline void inv3(const float* A, float* I) {
  float a=A[0],b=A[1],c=A[2],d=A[3],e=A[4],f=A[5],g=A[6],h=A[7],i=A[8];
  float c00 = e*i - f*h;
  float c01 = -(d*i - f*g);
  float c02 = d*h - e*g;
  float det = a*c00 + b*c01 + c*c02;
  float r = 1.0f / det;
  I[0] = c00*r;           I[1] = (c*h - b*i)*r;  I[2] = (b*f - c*e)*r;
  I[3] = c01*r;           I[4] = (a*i - c*g)*r;  I[5] = (c*d - a*f)*r;
  I[6] = c02*r;           I[7] = (b*g - a*h)*r;  I[8] = (a*e - b*d)*r;
}

// ---------- transpose+convert feats [N,C,HF,WF] f32 -> [N,HF,WF,C] f16 ----------
__global__ __launch_bounds__(256)
void transpose_feats_kernel(const float* __restrict__ f, _Float16* __restrict__ ft) {
  int idx = blockIdx.x * 256 + threadIdx.x;
  if (idx >= kNImgs * kFeatPerImg) return;
  int n  = idx / kFeatPerImg;
  int r  = idx - n * kFeatPerImg;
  int c  = r / kFeatPix;
  int yx = r - c * kFeatPix;
  ft[((size_t)n * kFeatPix + yx) * kC + c] = (_Float16)f[idx];
}

// ---------- main fused kernel ----------
// block = (ref n, d-half, p-group); lanes d-major (wave = 32 d x 2 p) so a
// wave's gathers walk an epipolar segment (sub-pixel step -> line sharing).
// Inner loop: v_pk_fma_f16 over natural channel pairs (no cross-register
// packs), f32 edge accumulation. Plain loop (R8 lesson: no manual pipeline);
// VGPR must stay <= 64 (R9 lesson: cliff halves occupancy).
template <bool TR>
__global__ __launch_bounds__(256)
void psv_var_kernel(const float* __restrict__ feats,      // [N,C,HF,WF] f32 (!TR)
                    const _Float16* __restrict__ featsT,  // [N,HF,WF,C] f16 (TR)
                    const float* __restrict__ rotmats,    // [N,3,3]
                    const float* __restrict__ tvecs,      // [N,3]
                    const float* __restrict__ Kmat,       // [N,3,3]
                    const int*   __restrict__ edges,      // [2,72]
                    float* __restrict__ out) {            // [N,C,D,HD,WD]
  __shared__ float sM[kEdgesPerRef][9];
  __shared__ float sB[kEdgesPerRef][3];
  __shared__ int   sSrc[kEdgesPerRef];
  __shared__ int   sUIdx[kEdgesPerRef];
  __shared__ float sMult[kEdgesPerRef];
  __shared__ int   sKU;
  __shared__ float sT[kC / 2][kPTile][kDTile + 2];  // 12-ch phase, 13 KB

  // bijective XCD-chunk swizzle (m204 formula; works for any gridDim)
  const int nwg = gridDim.x;
  const int orig = blockIdx.x;
  const int q = nwg >> 3, r8 = nwg & 7;
  const int xcd = orig & 7, lin = orig >> 3;
  const int bid = ((xcd < r8) ? xcd * (q + 1) : r8 * (q + 1) + (xcd - r8) * q) + lin;

  const int n     = bid / kBlocksPerRef;
  const int rem   = bid - n * kBlocksPerRef;
  const int dHalf = rem / kPGroups;
  const int pG    = rem - dHalf * kPGroups;

  const int t = threadIdx.x;

  if (t < kEdgesPerRef) {
    const int e  = n * kEdgesPerRef + t;
    const int re = edges[e];            // ref row
    const int se = edges[kNEdges + e];  // src row
    sSrc[t] = se;

    const float* Rr = rotmats + re * 9;
    const float* Rs = rotmats + se * 9;
    const float* Kr = Kmat + re * 9;
    const float* Ks = Kmat + se * 9;
    const float* tr = tvecs + re * 3;
    const float* ts = tvecs + se * 3;

    float RrT[9];
#pragma unroll
    for (int i = 0; i < 3; ++i)
#pragma unroll
      for (int j = 0; j < 3; ++j) RrT[i*3+j] = Rr[j*3+i];

    float Kinv[9], A[9], T1[9], M[9];
    inv3(Kr, Kinv);
    mm3(Rs, RrT, A);       // A = R_src * R_ref^T
    mm3(A, Kinv, T1);
    mm3(Ks, T1, M);        // M = K_src * A * K_ref^-1

    float At0 = A[0]*tr[0] + A[1]*tr[1] + A[2]*tr[2];
    float At1 = A[3]*tr[0] + A[4]*tr[1] + A[5]*tr[2];
    float At2 = A[6]*tr[0] + A[7]*tr[1] + A[8]*tr[2];
    float bv0 = ts[0] - At0, bv1 = ts[1] - At1, bv2 = ts[2] - At2;
#pragma unroll
    for (int i = 0; i < 9; ++i) sM[t][i] = M[i];
#pragma unroll
    for (int i = 0; i < 3; ++i)
      sB[t][i] = Ks[i*3+0]*bv0 + Ks[i*3+1]*bv1 + Ks[i*3+2]*bv2;
  }
  __syncthreads();

  if (t == 0) {
    int k = 0;
    for (int j = 0; j < kEdgesPerRef; ++j) {
      const int s = sSrc[j];
      bool dup = false;
      for (int i = 0; i < k; ++i) {
        if (sSrc[sUIdx[i]] == s) { sMult[i] += 1.0f; dup = true; break; }
      }
      if (!dup) { sUIdx[k] = j; sMult[k] = 1.0f; ++k; }
    }
    sKU = k;
  }
  __syncthreads();

  // d-major lane mapping
  const int dsub = t & 31;
  const int psub = t >> 5;
  const int d = dHalf * kDTile + dsub;
  const int p = pG * kPTile + psub;
  const int h = p / kWD;
  const int w = p - h * kWD;

  const float u = (float)w * (447.0f / 55.0f);   // linspace(0,447,56)
  const float v = (float)h * (447.0f / 55.0f);
  const float depth = 0.5f + 0.05f * (float)d;

  float2v acc2[kC / 2], accsq2[kC / 2];
#pragma unroll
  for (int i = 0; i < kC / 2; ++i) {
    acc2[i] = (float2v){0.0f, 0.0f};
    accsq2[i] = (float2v){0.0f, 0.0f};
  }

  const int kU = sKU;

  for (int jj = 0; jj < kU; ++jj) {
    const int j = sUIdx[jj];
    const float mult = sMult[jj];
    const float* M = sM[j];
    const float px = depth * (M[0]*u + M[1]*v + M[2]) + sB[j][0];
    const float py = depth * (M[3]*u + M[4]*v + M[5]) + sB[j][1];
    const float pz = depth * (M[6]*u + M[7]*v + M[8]) + sB[j][2];
    const float rz = 1.0f / (fabsf(pz) + 1e-8f);

    const float x = px * rz * (111.0f / 447.0f);
    const float y = py * rz * (111.0f / 447.0f);

    const float x0 = floorf(x), y0 = floorf(y);
    const float wx = x - x0, wy = y - y0;
    const bool vx0 = (x0 >= 0.0f)  && (x0 <= 111.0f);
    const bool vx1 = (x0 >= -1.0f) && (x0 <= 110.0f);
    const bool vy0 = (y0 >= 0.0f)  && (y0 <= 111.0f);
    const bool vy1 = (y0 >= -1.0f) && (y0 <= 110.0f);
    const float w00 = (vx0 && vy0) ? (1.0f - wx) * (1.0f - wy) : 0.0f;
    const float w01 = (vx1 && vy0) ? wx * (1.0f - wy) : 0.0f;
    const float w10 = (vx0 && vy1) ? (1.0f - wx) * wy : 0.0f;
    const float w11 = (vx1 && vy1) ? wx * wy : 0.0f;

    const int xc0 = (int)fminf(fmaxf(x0,        0.0f), 111.0f);
    const int xc1 = (int)fminf(fmaxf(x0 + 1.0f, 0.0f), 111.0f);
    const int yc0 = (int)fminf(fmaxf(y0,        0.0f), 111.0f);
    const int yc1 = (int)fminf(fmaxf(y0 + 1.0f, 0.0f), 111.0f);

    const int src = sSrc[j];
    if constexpr (TR) {
      // broadcast f16 weight pairs; taps accumulate via v_pk_fma_f16 on
      // natural channel pairs (32-bit sub-registers of the 16B loads).
      const _Float16 h00 = (_Float16)w00, h01 = (_Float16)w01;
      const _Float16 h10 = (_Float16)w10, h11 = (_Float16)w11;
      const half2v w00p = {h00, h00}, w01p = {h01, h01};
      const half2v w10p = {h10, h10}, w11p = {h11, h11};
      const float2v mult2 = {mult, mult};
      const _Float16* base = featsT + (size_t)src * kFeatPix * kC;
      const int o00 = (yc0 * kWF + xc0) * kC;
      const int o01 = (yc0 * kWF + xc1) * kC;
      const int o10 = (yc1 * kWF + xc0) * kC;
      const int o11 = (yc1 * kWF + xc1) * kC;
#pragma unroll
      for (int i = 0; i < kC / 8; ++i) {          // 3 chunks of 8 f16 channels
        const uint4v q00 = *(const uint4v*)(base + o00 + 8*i);
        const uint4v q01 = *(const uint4v*)(base + o01 + 8*i);
        const uint4v q10 = *(const uint4v*)(base + o10 + 8*i);
        const uint4v q11 = *(const uint4v*)(base + o11 + 8*i);
#pragma unroll
        for (int k2 = 0; k2 < 4; ++k2) {          // 2-channel sub-vectors
          const half2v val2h = u2h(q00[k2]) * w00p + u2h(q01[k2]) * w01p
                             + u2h(q10[k2]) * w10p + u2h(q11[k2]) * w11p;
          const float2v val2 = {(float)val2h[0], (float)val2h[1]};
          const float2v mval2 = mult2 * val2;
          const int idx = i*4 + k2;
          acc2[idx] += mval2;
          accsq2[idx] = mval2 * val2 + accsq2[idx];
        }
      }
    } else {
      const float* base = feats + (size_t)src * kFeatPerImg;
      const int o00 = yc0 * kWF + xc0;
      const int o01 = yc0 * kWF + xc1;
      const int o10 = yc1 * kWF + xc0;
      const int o11 = yc1 * kWF + xc1;
#pragma unroll
      for (int i = 0; i < kC / 2; ++i) {
#pragma unroll
        for (int kk = 0; kk < 2; ++kk) {
          const int c = 2*i + kk;
          const float* bc = base + (size_t)c * kFeatPix;
          float val = w00*bc[o00] + w01*bc[o01] + w10*bc[o10] + w11*bc[o11];
          const float mval = mult * val;
          acc2[i][kk] += mval;
          accsq2[i][kk] = __builtin_fmaf(mval, val, accsq2[i][kk]);
        }
      }
    }
  }

  // ---- epilogue: LDS transpose (d-major lanes -> p-coalesced stores) ----
  // two phases of 12 channels; 2 barriers each.
  const int pp2 = t & (kPTile - 1);   // store-side pixel index (0..7)
  const int dd2 = t >> 3;             // store-side depth index (0..31)
  const size_t outBase = (size_t)n * kC * (size_t)kPtsPerRef;
#pragma unroll
  for (int ph = 0; ph < 2; ++ph) {
    __syncthreads();               // protect previous phase's reads
#pragma unroll
    for (int cc = 0; cc < kC / 2; ++cc) {
      const int c = ph * (kC / 2) + cc;
      const float a = acc2[c >> 1][c & 1];
      const float s = accsq2[c >> 1][c & 1];
      const float mean = a * 0.125f;
      sT[cc][psub][dsub] = s * 0.125f - mean * mean;
    }
    __syncthreads();
#pragma unroll
    for (int cc = 0; cc < kC / 2; ++cc) {
      const int c = ph * (kC / 2) + cc;
      out[outBase + ((size_t)c * kNPlanes + (dHalf * kDTile + dd2)) * kNPix
          + pG * kPTile + pp2] = sT[cc][pp2][dd2];
    }
  }
}

extern "C" void kernel_launch(void* const* d_in, const int* in_sizes, int n_in,
                              void* d_out, int out_size, void* d_ws, size_t ws_size,
                              hipStream_t stream) {
  const float* feats  = (const float*)d_in[0];
  const float* rot    = (const float*)d_in[1];
  const float* tv     = (const float*)d_in[2];
  const float* Kmat   = (const float*)d_in[3];
  const int*   edges  = (const int*)d_in[4];
  float* out = (float*)d_out;

  const size_t featsTBytes = (size_t)kNImgs * kFeatPix * kC * sizeof(_Float16);  // 5.4 MB
  const int gridMain = kNImgs * kBlocksPerRef;     // 7056 blocks of 256 threads

  if (ws_size >= featsTBytes) {
    _Float16* featsT = (_Float16*)d_ws;
    const int nT = kNImgs * kFeatPerImg;           // 2,709,504
    transpose_feats_kernel<<<(nT + 255) / 256, 256, 0, stream>>>(feats, featsT);
    psv_var_kernel<true><<<gridMain, 256, 0, stream>>>(feats, featsT, rot, tv, Kmat, edges, out);
  } else {
    psv_var_kernel<false><<<gridMain, 256, 0, stream>>>(feats, nullptr, rot, tv, Kmat, edges, out);
  }
}